// Round 1
// baseline (339.052 us; speedup 1.0000x reference)
//
#include <hip/hip_runtime.h>
#include <hip/hip_bf16.h>

typedef __attribute__((ext_vector_type(8))) short short8;
typedef __attribute__((ext_vector_type(4))) float f32x4;

#define LN10000_DIV32 0.2878231366242558f

__device__ __forceinline__ unsigned short f2bf(float f){
  union { float fv; unsigned u; } a; a.fv = f;
  return (unsigned short)((a.u + 0x7fffu + ((a.u >> 16) & 1u)) >> 16);
}

// ---------------- convert fp32 -> bf16 (x, W_Q|W_K|W_V fused, W_O) ----------------
__global__ __launch_bounds__(256) void convert_all(
    const float* __restrict__ x, const float* __restrict__ wq,
    const float* __restrict__ wk, const float* __restrict__ wv,
    const float* __restrict__ wo, unsigned short* __restrict__ dst)
{
  size_t t = (size_t)blockIdx.x * 256 + threadIdx.x;
  size_t e = t * 8;
  const float* src; size_t off;
  if (e < 4194304UL)      { src = x;  off = e; }
  else if (e < 5242880UL) { src = wq; off = e - 4194304UL; }
  else if (e < 6291456UL) { src = wk; off = e - 5242880UL; }
  else if (e < 7340032UL) { src = wv; off = e - 6291456UL; }
  else                    { src = wo; off = e - 7340032UL; }
  float4 f0 = *(const float4*)(src + off);
  float4 f1 = *(const float4*)(src + off + 4);
  short8 o;
  o[0] = (short)f2bf(f0.x); o[1] = (short)f2bf(f0.y);
  o[2] = (short)f2bf(f0.z); o[3] = (short)f2bf(f0.w);
  o[4] = (short)f2bf(f1.x); o[5] = (short)f2bf(f1.y);
  o[6] = (short)f2bf(f1.z); o[7] = (short)f2bf(f1.w);
  *(short8*)(dst + e) = o;
}

// ---------------- m97-style 128x128 bf16 GEMM mainloop (Y = A * B^T) ----------------
// A: [M][1024] bf16 row-major, B: [N][1024] bf16 row-major (both K-contiguous).
// 256 threads = 4 waves; wave (wm,wn) computes 64x64; acc[mf][nf] 16x16 fragments.
__device__ __forceinline__ void gemm_mainloop(
    const unsigned short* __restrict__ A, const unsigned short* __restrict__ B,
    int m0, int n0, unsigned short* As, unsigned short* Bs, f32x4 acc[4][4])
{
  const int tid  = threadIdx.x;
  const int lane = tid & 63;
  const int w    = tid >> 6;
  const int wm = w >> 1, wn = w & 1;
  const int fr = lane & 15, fq = lane >> 4;
  const int srow = lane >> 2;        // row within 16-row staging chunk
  const int scol = (lane & 3) * 8;   // k offset within 32
  for (int kt = 0; kt < 32; ++kt){
    const int k0 = kt * 32;
    #pragma unroll
    for (int i = 0; i < 2; ++i){
      const int c = w * 2 + i;       // 8 chunks of 16 rows
      const unsigned short* ga = A + (size_t)(m0 + c*16 + srow) * 1024 + k0 + scol;
      const unsigned short* gb = B + (size_t)(n0 + c*16 + srow) * 1024 + k0 + scol;
      __builtin_amdgcn_global_load_lds((const __attribute__((address_space(1))) void*)ga,
                                       (__attribute__((address_space(3))) void*)(As + c*512), 16, 0, 0);
      __builtin_amdgcn_global_load_lds((const __attribute__((address_space(1))) void*)gb,
                                       (__attribute__((address_space(3))) void*)(Bs + c*512), 16, 0, 0);
    }
    __syncthreads();
    short8 af[4], bfv[4];
    #pragma unroll
    for (int mf = 0; mf < 4; ++mf)
      af[mf] = *(const short8*)(As + (wm*64 + mf*16 + fr) * 32 + fq * 8);
    #pragma unroll
    for (int nf = 0; nf < 4; ++nf)
      bfv[nf] = *(const short8*)(Bs + (wn*64 + nf*16 + fr) * 32 + fq * 8);
    #pragma unroll
    for (int mf = 0; mf < 4; ++mf)
      #pragma unroll
      for (int nf = 0; nf < 4; ++nf)
        acc[mf][nf] = __builtin_amdgcn_mfma_f32_16x16x32_bf16(af[mf], bfv[nf], acc[mf][nf], 0, 0, 0);
    __syncthreads();
  }
}

// ---------------- QKV projection + RoPE + layout transform ----------------
// Y[m][n], m = b*2048+s, n in [0,3072): seg = n>>10 (0:Q 1:K 2:V), h = (n&1023)>>6, d = n&63.
// Q,K -> [bh][s][64] with RoPE; V -> transposed [bh][64][s].
__global__ __launch_bounds__(256) void gemm_qkv(
    const unsigned short* __restrict__ Xb, const unsigned short* __restrict__ Wb,
    const int* __restrict__ positions,
    unsigned short* __restrict__ Qb, unsigned short* __restrict__ Kb,
    unsigned short* __restrict__ Vtb)
{
  __shared__ unsigned short As[4096], Bs[4096];
  f32x4 acc[4][4] = {};
  const int m0 = blockIdx.y * 128, n0 = blockIdx.x * 128;
  gemm_mainloop(Xb, Wb, m0, n0, As, Bs, acc);
  const int lane = threadIdx.x & 63;
  const int w = threadIdx.x >> 6, wm = w >> 1, wn = w & 1;
  const int fr = lane & 15, fq = lane >> 4;
  #pragma unroll
  for (int mf = 0; mf < 4; ++mf){
    #pragma unroll
    for (int nf = 0; nf < 4; ++nf){
      const int n = n0 + wn*64 + nf*16 + fr;
      const int seg = n >> 10;                // uniform across the wave
      const int h = (n & 1023) >> 6, d = n & 63;
      #pragma unroll
      for (int r = 0; r < 4; ++r){
        const int m = m0 + wm*64 + mf*16 + fq*4 + r;
        const int b = m >> 11, s = m & 2047;
        float v = acc[mf][nf][r];
        float outv = v;
        if (seg < 2){
          // RoPE: even/odd feature pair lives in adjacent lanes (cols)
          float pv = __shfl_xor(v, 1);
          const int ip = d >> 1;
          float invf = __expf(-(float)ip * LN10000_DIV32); // 10000^(-ip/32)
          float ang = (float)positions[m] * invf;
          float sv = __sinf(ang), cv = __cosf(ang);
          outv = (d & 1) ? (cv * v + sv * pv)   // odd: sin*even + cos*odd
                         : (cv * v - sv * pv);  // even: cos*even - sin*odd
        }
        const unsigned short ob = f2bf(outv);
        const size_t bh = (size_t)b * 16 + h;
        if (seg == 0)      Qb[(bh*2048 + s)*64 + d] = ob;
        else if (seg == 1) Kb[(bh*2048 + s)*64 + d] = ob;
        else               Vtb[(bh*64 + d)*2048 + s] = ob;
      }
    }
  }
}

// ---------------- causal flash attention ----------------
// grid: (32 q-tiles of 64, 32 bh). 4 waves/block, each owns 16 q rows, no cross-wave sync.
__global__ __launch_bounds__(256) void attn_kernel(
    const unsigned short* __restrict__ Qb, const unsigned short* __restrict__ Kb,
    const unsigned short* __restrict__ Vtb, unsigned short* __restrict__ Ob)
{
  __shared__ unsigned short Plds[4][16][32];   // per-wave P bounce buffer
  const int tid = threadIdx.x, lane = tid & 63, w = tid >> 6;
  const int fr = lane & 15, fq = lane >> 4;
  const int bh = blockIdx.y;
  const int b = bh >> 4, h = bh & 15;
  const int q0 = blockIdx.x * 64 + w * 16;     // this wave's 16 q rows
  const size_t qk_base = (size_t)bh * 2048 * 64;

  // Q fragments: row = q0+fr, k(d) = fq*8..+8 and +32
  const unsigned short* qp = Qb + qk_base + (size_t)(q0 + fr) * 64 + fq * 8;
  short8 aq0 = *(const short8*)qp;
  short8 aq1 = *(const short8*)(qp + 32);

  f32x4 accO[4] = {};
  float mrun[4], lrun[4];
  #pragma unroll
  for (int r = 0; r < 4; ++r){ mrun[r] = -1e30f; lrun[r] = 0.f; }

  const int kv_end = q0 + 16;                  // causal upper bound for this wave
  for (int kv0 = 0; kv0 < kv_end; kv0 += 32){
    // S = Q K^T for 32 kv cols (two 16-col fragments)
    f32x4 sf[2];
    #pragma unroll
    for (int hf = 0; hf < 2; ++hf){
      const unsigned short* kp = Kb + qk_base + (size_t)(kv0 + hf*16 + fr) * 64 + fq * 8;
      short8 bk0 = *(const short8*)kp;
      short8 bk1 = *(const short8*)(kp + 32);
      f32x4 s = {0.f, 0.f, 0.f, 0.f};
      s = __builtin_amdgcn_mfma_f32_16x16x32_bf16(aq0, bk0, s, 0, 0, 0);
      s = __builtin_amdgcn_mfma_f32_16x16x32_bf16(aq1, bk1, s, 0, 0, 0);
      sf[hf] = s;
    }
    // scale + causal mask
    #pragma unroll
    for (int hf = 0; hf < 2; ++hf)
      #pragma unroll
      for (int r = 0; r < 4; ++r){
        float v = sf[hf][r] * 0.125f;
        const int qrow  = q0 + fq*4 + r;
        const int kvcol = kv0 + hf*16 + fr;
        sf[hf][r] = (kvcol > qrow) ? -1e30f : v;
      }
    // online softmax (row = 16 lanes of one quarter-wave)
    float pw0[4], pw1[4];
    #pragma unroll
    for (int r = 0; r < 4; ++r){
      float t = fmaxf(sf[0][r], sf[1][r]);
      #pragma unroll
      for (int off = 1; off < 16; off <<= 1)
        t = fmaxf(t, __shfl_xor(t, off));
      const float mnew = fmaxf(mrun[r], t);
      const float sc = __expf(mrun[r] - mnew);
      const float p0 = __expf(sf[0][r] - mnew);
      const float p1 = __expf(sf[1][r] - mnew);
      float rs = p0 + p1;
      #pragma unroll
      for (int off = 1; off < 16; off <<= 1)
        rs += __shfl_xor(rs, off);
      lrun[r] = lrun[r] * sc + rs;
      mrun[r] = mnew;
      pw0[r] = p0; pw1[r] = p1;
      #pragma unroll
      for (int dblk = 0; dblk < 4; ++dblk)
        accO[dblk][r] *= sc;
    }
    // P (D-layout) -> LDS -> A-layout fragment
    #pragma unroll
    for (int r = 0; r < 4; ++r){
      Plds[w][fq*4 + r][fr]      = f2bf(pw0[r]);
      Plds[w][fq*4 + r][16 + fr] = f2bf(pw1[r]);
    }
    asm volatile("s_waitcnt lgkmcnt(0)" ::: "memory");
    short8 ap = *(const short8*)&Plds[w][fr][fq * 8];
    // O += P * V   (V^T layout: one contiguous bf16x8 per fragment)
    #pragma unroll
    for (int dblk = 0; dblk < 4; ++dblk){
      const unsigned short* vp = Vtb + ((size_t)bh*64 + dblk*16 + fr) * 2048 + kv0 + fq * 8;
      short8 bv = *(const short8*)vp;
      accO[dblk] = __builtin_amdgcn_mfma_f32_16x16x32_bf16(ap, bv, accO[dblk], 0, 0, 0);
    }
  }
  // epilogue: O[b][s][h*64+d] bf16
  #pragma unroll
  for (int dblk = 0; dblk < 4; ++dblk)
    #pragma unroll
    for (int r = 0; r < 4; ++r){
      const int s = q0 + fq*4 + r;
      const float o = accO[dblk][r] / lrun[r];
      Ob[((size_t)b*2048 + s)*1024 + h*64 + dblk*16 + fr] = f2bf(o);
    }
}

// ---------------- output projection -> fp32 d_out ----------------
__global__ __launch_bounds__(256) void gemm_out(
    const unsigned short* __restrict__ Obf, const unsigned short* __restrict__ Wb,
    float* __restrict__ out)
{
  __shared__ unsigned short As[4096], Bs[4096];
  f32x4 acc[4][4] = {};
  const int m0 = blockIdx.y * 128, n0 = blockIdx.x * 128;
  gemm_mainloop(Obf, Wb, m0, n0, As, Bs, acc);
  const int lane = threadIdx.x & 63;
  const int w = threadIdx.x >> 6, wm = w >> 1, wn = w & 1;
  const int fr = lane & 15, fq = lane >> 4;
  #pragma unroll
  for (int mf = 0; mf < 4; ++mf)
    #pragma unroll
    for (int nf = 0; nf < 4; ++nf){
      const int n = n0 + wn*64 + nf*16 + fr;
      #pragma unroll
      for (int r = 0; r < 4; ++r){
        const int m = m0 + wm*64 + mf*16 + fq*4 + r;
        out[(size_t)m * 1024 + n] = acc[mf][nf][r];
      }
    }
}

extern "C" void kernel_launch(void* const* d_in, const int* in_sizes, int n_in,
                              void* d_out, int out_size, void* d_ws, size_t ws_size,
                              hipStream_t stream) {
  const float* x  = (const float*)d_in[0];
  const int* pos  = (const int*)d_in[1];
  const float* wq = (const float*)d_in[2];
  const float* wk = (const float*)d_in[3];
  const float* wv = (const float*)d_in[4];
  const float* wo = (const float*)d_in[5];
  float* out = (float*)d_out;

  unsigned short* ws = (unsigned short*)d_ws;
  unsigned short* Xb   = ws;                  // 4096x1024
  unsigned short* Wqkv = ws + 4194304UL;      // 3072x1024
  unsigned short* Wo   = ws + 7340032UL;      // 1024x1024
  unsigned short* Qb   = ws + 8388608UL;      // [32][2048][64]
  unsigned short* Kb   = ws + 12582912UL;     // [32][2048][64]
  unsigned short* Vt   = ws + 16777216UL;     // [32][64][2048]
  unsigned short* Ob   = ws + 20971520UL;     // 4096x1024

  convert_all<<<4096, 256, 0, stream>>>(x, wq, wk, wv, wo, ws);

  dim3 g1(24, 32);
  gemm_qkv<<<g1, 256, 0, stream>>>(Xb, Wqkv, pos, Qb, Kb, Vt);

  dim3 g2(32, 32);
  attn_kernel<<<g2, 256, 0, stream>>>(Qb, Kb, Vt, Ob);

  dim3 g3(8, 32);
  gemm_out<<<g3, 256, 0, stream>>>(Ob, Wo, out);
}